// Round 8
// baseline (442.302 us; speedup 1.0000x reference)
//
#include <hip/hip_runtime.h>
#include <stdint.h>

#define B_SZ 8192
#define D_SZ 1024
#define L_SZ 64
#define H_SZ 256

#define BM 256
#define BN 256
#define BK 64

typedef __attribute__((ext_vector_type(8))) __bf16 bf16x8;
typedef __attribute__((ext_vector_type(4))) float f32x4;

typedef __attribute__((address_space(1))) void as1_void;
typedef __attribute__((address_space(3))) void as3_void;

static __device__ __forceinline__ void gload_lds16(const void* g, void* l) {
    __builtin_amdgcn_global_load_lds((as1_void*)g, (as3_void*)l, 16, 0, 0);
}

static __device__ __forceinline__ unsigned short f2bf(float f) {
    uint32_t u = __builtin_bit_cast(uint32_t, f);
    u += 0x7fffu + ((u >> 16) & 1u);
    return (unsigned short)(u >> 16);
}

// ---------------- prep: x (fp32 [B][D]) -> bf16 ----------------
__global__ void cvt_x_kernel(const float* __restrict__ x, unsigned short* __restrict__ xb) {
    int i = blockIdx.x * blockDim.x + threadIdx.x;
    const float4 v = reinterpret_cast<const float4*>(x)[i];
    ushort4 o;
    o.x = f2bf(v.x); o.y = f2bf(v.y); o.z = f2bf(v.z); o.w = f2bf(v.w);
    reinterpret_cast<ushort4*>(xb)[i] = o;
}

// ------- prep: W1 (fp32 [L][D][H]) -> W1T bf16 [L][H][D] -------
__global__ void transpose_w1_kernel(const float* __restrict__ w1, unsigned short* __restrict__ w1t) {
    __shared__ float tile[64][65];
    int b = blockIdx.x;
    int l  = b >> 6;
    int dt = (b >> 2) & 15;
    int ht = b & 3;
    int tx = threadIdx.x & 63;
    int ty = threadIdx.x >> 6;
    const float* src = w1 + (size_t)l * (D_SZ * H_SZ);
    #pragma unroll
    for (int r = 0; r < 64; r += 4)
        tile[r + ty][tx] = src[(size_t)(dt * 64 + r + ty) * H_SZ + ht * 64 + tx];
    __syncthreads();
    unsigned short* dst = w1t + (size_t)l * (H_SZ * D_SZ);
    #pragma unroll
    for (int r = 0; r < 64; r += 4)
        dst[(size_t)(ht * 64 + r + ty) * D_SZ + dt * 64 + tx] = f2bf(tile[tx][r + ty]);
}

// ---- fused label-wise FFN GEMM: 256x256, A-only LDS, B global->reg dbuf ----
// grid: (B/256)*L = 2048 blocks, 512 threads (8 waves, 2M x 4N).
// R2-proven A staging/swizzle/fragments; B fragments loaded straight from
// XCD-L2-resident W1T panel into registers (double-buffered by tile parity).

#define SBAR asm volatile("s_barrier" ::: "memory")
#define VMW(n) asm volatile("s_waitcnt vmcnt(" #n ")" ::: "memory")

#define DS_READ_A(c, quad) do { \
    _Pragma("unroll") for (int j = 0; j < 2; ++j) { \
        const int rowh = ((quad)*2 + j)*16 + rl; \
        _Pragma("unroll") for (int ks = 0; ks < 2; ++ks) { \
            const int slot = (ks*4 + g) ^ (rowh & 7); \
            af[ks][j] = *reinterpret_cast<const bf16x8*>( \
                reinterpret_cast<const char*>(&ldsA[c][wr][0]) + rowh*128 + slot*16); \
        } } } while(0)

// B frags for tile t into breg[2][4] (plain loads -> compiler-tracked vmcnt).
// elem offset = (l*256+col)*1024 + t*64 + ks*32 + g*8  == LDS-version mapping.
#define LOAD_B(breg, t) do { \
    _Pragma("unroll") for (int nf = 0; nf < 4; ++nf) \
    _Pragma("unroll") for (int ks = 0; ks < 2; ++ks) \
        breg[ks][nf] = bPtr[nf][(size_t)(t) * 8 + ks * 4]; \
} while(0)

#define MFMA_QUAD(quad, breg) do { \
    __builtin_amdgcn_s_setprio(1); \
    _Pragma("unroll") for (int ks = 0; ks < 2; ++ks) \
    _Pragma("unroll") for (int j = 0; j < 2; ++j) \
    _Pragma("unroll") for (int nf = 0; nf < 4; ++nf) \
        acc[(quad)*2 + j][nf] = __builtin_amdgcn_mfma_f32_16x16x32_bf16( \
            af[ks][j], breg[ks][nf], acc[(quad)*2 + j][nf], 0, 0, 0); \
    __builtin_amdgcn_s_setprio(0); } while(0)

#define STAGE_A(t, h) do { \
    gload_lds16(aSrc[h][0] + (size_t)(t)*BK, &ldsA[(t)&1][h][(wid*64)*8]); \
    gload_lds16(aSrc[h][1] + (size_t)(t)*BK, &ldsA[(t)&1][h][(512 + wid*64)*8]); } while(0)

__global__ __launch_bounds__(512, 2) void ffn_gemm_kernel(
    const unsigned short* __restrict__ xb,    // bf16 [B][D]
    const unsigned short* __restrict__ w1t,   // bf16 [L][H][D]
    const float* __restrict__ b1,             // [L][H]
    const float* __restrict__ w2,             // [L][H]
    const float* __restrict__ b2,             // [L]
    float* __restrict__ out)                  // f32 [B][L]
{
    // A only: [dbuf][half][128 rows * 64 K] bf16 = 64 KiB  (+1 KB red) 
    __shared__ unsigned short ldsA[2][2][128 * 64];
    __shared__ float partRed[256][4];

    // bijective XCD swizzle (2048 % 8 == 0): 32 consecutive wgs share one
    // label -> W1T_l panel (512 KB) hot in that XCD's L2 (B reads hit L2).
    const int bid = blockIdx.x;
    const int wg  = ((bid & 7) << 8) + (bid >> 3);
    const int l   = wg >> 5;
    const int m0  = (wg & 31) * BM;

    const int tid  = threadIdx.x;
    const int wid  = tid >> 6;
    const int lane = tid & 63;
    const int wr   = wid >> 2;   // 0..1
    const int wc   = wid & 3;    // 0..3
    const int g    = lane >> 4;  // 0..3
    const int rl   = lane & 15;

    // Pre-swizzled A global sources (rule #21), exactly R2's
    const unsigned short* aSrc[2][2];
    #pragma unroll
    for (int h = 0; h < 2; ++h)
        #pragma unroll
        for (int c2 = 0; c2 < 2; ++c2) {
            const int q  = c2 * 512 + tid;
            const int r  = q >> 3;
            const int kg = (q & 7) ^ (r & 7);
            aSrc[h][c2] = xb + (size_t)(m0 + h * 128 + r) * D_SZ + kg * 8;
        }

    // Per-lane B fragment base pointers (bf16x8 units), one per nf
    const bf16x8* bPtr[4];
    #pragma unroll
    for (int nf = 0; nf < 4; ++nf) {
        const int col = wc * 64 + nf * 16 + rl;
        bPtr[nf] = reinterpret_cast<const bf16x8*>(
                       w1t + ((size_t)l * H_SZ + col) * D_SZ) + g;
    }

    // epilogue constants hoisted
    float b1v[4], w2v[4];
    #pragma unroll
    for (int nf = 0; nf < 4; ++nf) {
        const int col = wc * 64 + nf * 16 + rl;
        b1v[nf] = b1[l * H_SZ + col];
        w2v[nf] = w2[l * H_SZ + col];
    }
    const float b2v = b2[l];

    f32x4 acc[8][4];
    #pragma unroll
    for (int m = 0; m < 8; ++m)
        #pragma unroll
        for (int n = 0; n < 4; ++n) {
            acc[m][n][0] = 0.f; acc[m][n][1] = 0.f;
            acc[m][n][2] = 0.f; acc[m][n][3] = 0.f;
        }

    bf16x8 af[2][2];
    bf16x8 bregE[2][4], bregO[2][4];

    // Prologue: A(0) staged, B(0)+B(1) to regs; keep B(1)'s 8 in flight.
    STAGE_A(0, 0); STAGE_A(0, 1);     // 4 loads/thread
    LOAD_B(bregE, 0);                 // 8
    LOAD_B(bregO, 1);                 // 8
    VMW(8);                           // A(0), B(0) retired
    SBAR;

    // Steady state per tile t: stage A(t+1) in P0/P1 (opposite LDS parity),
    // load B(t+2) after the last MFMA consuming breg(t) (no reg overlap),
    // VMW(8) retires A(t+1)+B(t+1), keeps B(t+2) in flight. 4 ds_read/phase.
    #pragma unroll 1
    for (int i = 0; i < 7; ++i) {
        const int e = 2 * i, o = 2 * i + 1;
        // tile e (LDS buf 0, bregE)
        DS_READ_A(0, 0); STAGE_A(e + 1, 0); SBAR; MFMA_QUAD(0, bregE); SBAR;
        DS_READ_A(0, 1); STAGE_A(e + 1, 1); SBAR; MFMA_QUAD(1, bregE); SBAR;
        DS_READ_A(0, 2);                    SBAR; MFMA_QUAD(2, bregE); SBAR;
        DS_READ_A(0, 3);                    SBAR; MFMA_QUAD(3, bregE);
        LOAD_B(bregE, e + 2); VMW(8); SBAR;
        // tile o (LDS buf 1, bregO)
        DS_READ_A(1, 0); STAGE_A(o + 1, 0); SBAR; MFMA_QUAD(0, bregO); SBAR;
        DS_READ_A(1, 1); STAGE_A(o + 1, 1); SBAR; MFMA_QUAD(1, bregO); SBAR;
        DS_READ_A(1, 2);                    SBAR; MFMA_QUAD(2, bregO); SBAR;
        DS_READ_A(1, 3);                    SBAR; MFMA_QUAD(3, bregO);
        LOAD_B(bregO, o + 2); VMW(8); SBAR;
    }
    // Tail: tiles 14, 15 — stage A(15) during 14; nothing else left.
    DS_READ_A(0, 0); STAGE_A(15, 0); SBAR; MFMA_QUAD(0, bregE); SBAR;
    DS_READ_A(0, 1); STAGE_A(15, 1); SBAR; MFMA_QUAD(1, bregE); SBAR;
    DS_READ_A(0, 2);                 SBAR; MFMA_QUAD(2, bregE); SBAR;
    DS_READ_A(0, 3);                 SBAR; MFMA_QUAD(3, bregE); VMW(0); SBAR;
    DS_READ_A(1, 0);                 SBAR; MFMA_QUAD(0, bregO); SBAR;
    DS_READ_A(1, 1);                 SBAR; MFMA_QUAD(1, bregO); SBAR;
    DS_READ_A(1, 2);                 SBAR; MFMA_QUAD(2, bregO); SBAR;
    DS_READ_A(1, 3);                 SBAR; MFMA_QUAD(3, bregO);

    // ---- fused epilogue: out[row, l] = sum_h relu(C + b1)*w2 + b2 ----
    #pragma unroll
    for (int mf = 0; mf < 8; ++mf) {
        #pragma unroll
        for (int r = 0; r < 4; ++r) {
            float p = 0.f;
            #pragma unroll
            for (int nf = 0; nf < 4; ++nf) {
                float v = acc[mf][nf][r] + b1v[nf];
                v = fmaxf(v, 0.f);
                p += v * w2v[nf];
            }
            p += __shfl_xor(p, 1);
            p += __shfl_xor(p, 2);
            p += __shfl_xor(p, 4);
            p += __shfl_xor(p, 8);
            if (rl == 0)
                partRed[wr * 128 + mf * 16 + g * 4 + r][wc] = p;
        }
    }
    __syncthreads();
    if (tid < BM) {
        float s = b2v;
        #pragma unroll
        for (int w = 0; w < 4; ++w) s += partRed[tid][w];
        out[(size_t)(m0 + tid) * L_SZ + l] = s;
    }
}

extern "C" void kernel_launch(void* const* d_in, const int* in_sizes, int n_in,
                              void* d_out, int out_size, void* d_ws, size_t ws_size,
                              hipStream_t stream) {
    const float* x  = (const float*)d_in[0];
    const float* W1 = (const float*)d_in[1];
    const float* b1 = (const float*)d_in[2];
    const float* W2 = (const float*)d_in[3];
    const float* b2 = (const float*)d_in[4];
    float* out = (float*)d_out;

    unsigned short* xb  = (unsigned short*)d_ws;                 // 16 MB
    unsigned short* w1t = xb + (size_t)B_SZ * D_SZ;              // 32 MB

    cvt_x_kernel<<<(B_SZ * D_SZ / 4) / 256, 256, 0, stream>>>(x, xb);
    transpose_w1_kernel<<<L_SZ * 16 * 4, 256, 0, stream>>>(W1, w1t);
    ffn_gemm_kernel<<<(B_SZ / BM) * L_SZ, 512, 0, stream>>>(xb, w1t, b1, W2, b2, out);
}

// Round 9
// 339.787 us; speedup vs baseline: 1.3017x; 1.3017x over previous
//
#include <hip/hip_runtime.h>
#include <stdint.h>

#define B_SZ 8192
#define D_SZ 1024
#define L_SZ 64
#define H_SZ 256

#define BM 256
#define BN 256
#define BK 32
#define NT (D_SZ / BK)   // 32 K-tiles

typedef __attribute__((ext_vector_type(8))) __bf16 bf16x8;
typedef __attribute__((ext_vector_type(4))) float f32x4;

typedef __attribute__((address_space(1))) void as1_void;
typedef __attribute__((address_space(3))) void as3_void;

static __device__ __forceinline__ void gload_lds16(const void* g, void* l) {
    __builtin_amdgcn_global_load_lds((as1_void*)g, (as3_void*)l, 16, 0, 0);
}

static __device__ __forceinline__ unsigned short f2bf(float f) {
    uint32_t u = __builtin_bit_cast(uint32_t, f);
    u += 0x7fffu + ((u >> 16) & 1u);
    return (unsigned short)(u >> 16);
}

// ---------------- prep: x (fp32 [B][D]) -> bf16 ----------------
__global__ void cvt_x_kernel(const float* __restrict__ x, unsigned short* __restrict__ xb) {
    int i = blockIdx.x * blockDim.x + threadIdx.x;
    const float4 v = reinterpret_cast<const float4*>(x)[i];
    ushort4 o;
    o.x = f2bf(v.x); o.y = f2bf(v.y); o.z = f2bf(v.z); o.w = f2bf(v.w);
    reinterpret_cast<ushort4*>(xb)[i] = o;
}

// ------- prep: W1 (fp32 [L][D][H]) -> W1T bf16 [L][H][D] -------
__global__ void transpose_w1_kernel(const float* __restrict__ w1, unsigned short* __restrict__ w1t) {
    __shared__ float tile[64][65];
    int b = blockIdx.x;
    int l  = b >> 6;
    int dt = (b >> 2) & 15;
    int ht = b & 3;
    int tx = threadIdx.x & 63;
    int ty = threadIdx.x >> 6;
    const float* src = w1 + (size_t)l * (D_SZ * H_SZ);
    #pragma unroll
    for (int r = 0; r < 64; r += 4)
        tile[r + ty][tx] = src[(size_t)(dt * 64 + r + ty) * H_SZ + ht * 64 + tx];
    __syncthreads();
    unsigned short* dst = w1t + (size_t)l * (H_SZ * D_SZ);
    #pragma unroll
    for (int r = 0; r < 64; r += 4)
        dst[(size_t)(ht * 64 + r + ty) * D_SZ + dt * 64 + tx] = f2bf(tile[tx][r + ty]);
}

// ---- fused label-wise FFN GEMM: 256x256, BK=32, 3-deep ring (A and B) ----
// grid: (B/256)*L = 2048 blocks, 512 threads (8 waves, 2M x 4N).
// Stage tile t+2 during tile t; VMW(4) per tile retires tile t+1's loads
// (issued a full tile earlier) -> the wait is structurally non-blocking.

#define SBAR asm volatile("s_barrier" ::: "memory")
#define VMW(n) asm volatile("s_waitcnt vmcnt(" #n ")" ::: "memory")

// A frags for half h (m = h*4 .. h*4+3): row = wr*128 + m*16 + rl
// slot = g ^ ((row>>1)&3)  (R7-verified zero-conflict family, 64B rows)
#define DS_A(cb, h) do { \
    _Pragma("unroll") for (int m = 0; m < 4; ++m) { \
        const int row = wr * 128 + ((h) * 4 + m) * 16 + rl; \
        const int slot = g ^ ((row >> 1) & 3); \
        af[m] = *reinterpret_cast<const bf16x8*>( \
            reinterpret_cast<const char*>(&ldsA[cb][0]) + row * 64 + slot * 16); \
    } } while(0)

#define DS_B(cb) do { \
    _Pragma("unroll") for (int n = 0; n < 4; ++n) { \
        const int row = wc * 64 + n * 16 + rl; \
        const int slot = g ^ ((row >> 1) & 3); \
        bfv[n] = *reinterpret_cast<const bf16x8*>( \
            reinterpret_cast<const char*>(&ldsB[cb][0]) + row * 64 + slot * 16); \
    } } while(0)

// 16 MFMA: acc rows h*4..h*4+3 x all 4 n  (one 16x16x32 covers full BK=32)
#define MFMA_H(h) do { \
    __builtin_amdgcn_s_setprio(1); \
    _Pragma("unroll") for (int m = 0; m < 4; ++m) \
    _Pragma("unroll") for (int n = 0; n < 4; ++n) \
        acc[(h) * 4 + m][n] = __builtin_amdgcn_mfma_f32_16x16x32_bf16( \
            af[m], bfv[n], acc[(h) * 4 + m][n], 0, 0, 0); \
    __builtin_amdgcn_s_setprio(0); } while(0)

// stage tile t into ring buf sb: 2 loads/thread each for A and B
#define STAGE_A(t, sb) do { \
    gload_lds16(aSrc[0] + (size_t)(t) * BK, (char*)&ldsA[sb][0] + tid * 16); \
    gload_lds16(aSrc[1] + (size_t)(t) * BK, (char*)&ldsA[sb][0] + 8192 + tid * 16); } while(0)
#define STAGE_B(t, sb) do { \
    gload_lds16(bSrc[0] + (size_t)(t) * BK, (char*)&ldsB[sb][0] + tid * 16); \
    gload_lds16(bSrc[1] + (size_t)(t) * BK, (char*)&ldsB[sb][0] + 8192 + tid * 16); } while(0)

// tile body: compute buf cb, stage tile t+2 into buf sb
#define TILE(t, cb, sb) do { \
    DS_A(cb, 0); DS_B(cb); STAGE_A((t) + 2, sb); SBAR; MFMA_H(0); SBAR; \
    DS_A(cb, 1);           STAGE_B((t) + 2, sb); SBAR; MFMA_H(1); VMW(4); SBAR; \
} while(0)

__global__ __launch_bounds__(512, 2) void ffn_gemm_kernel(
    const unsigned short* __restrict__ xb,    // bf16 [B][D]
    const unsigned short* __restrict__ w1t,   // bf16 [L][H][D]
    const float* __restrict__ b1,             // [L][H]
    const float* __restrict__ w2,             // [L][H]
    const float* __restrict__ b2,             // [L]
    float* __restrict__ out)                  // f32 [B][L]
{
    __shared__ unsigned short ldsA[3][BM * BK];   // 3 x 16 KB
    __shared__ unsigned short ldsB[3][BN * BK];   // 3 x 16 KB
    __shared__ float partRed[256][4];             // 4 KB -> 100 KB total

    // bijective XCD swizzle (2048 % 8 == 0): 32 consecutive wgs share one
    // label -> W1T_l panel (512 KB) hot in that XCD's L2.
    const int bid = blockIdx.x;
    const int wg  = ((bid & 7) << 8) + (bid >> 3);
    const int l   = wg >> 5;
    const int m0  = (wg & 31) * BM;

    const int tid  = threadIdx.x;
    const int wid  = tid >> 6;
    const int lane = tid & 63;
    const int wr   = wid >> 2;   // 0..1
    const int wc   = wid & 3;    // 0..3
    const int g    = lane >> 4;  // 0..3 (k-granule)
    const int rl   = lane & 15;

    // Pre-swizzled global sources (rule #21): granule kg of row r stored at
    // slot kg ^ ((r>>1)&3); DMA dest linear [row][slot].
    const unsigned short* aSrc[2];
    const unsigned short* bSrc[2];
    #pragma unroll
    for (int c2 = 0; c2 < 2; ++c2) {
        const int q  = c2 * 512 + tid;
        const int r  = q >> 2;                  // 0..255
        const int kg = (q & 3) ^ ((r >> 1) & 3);
        aSrc[c2] = xb  + (size_t)(m0 + r) * D_SZ + kg * 8;
        bSrc[c2] = w1t + ((size_t)l * H_SZ + r) * D_SZ + kg * 8;
    }

    // epilogue constants hoisted
    float b1v[4], w2v[4];
    #pragma unroll
    for (int n = 0; n < 4; ++n) {
        const int col = wc * 64 + n * 16 + rl;
        b1v[n] = b1[l * H_SZ + col];
        w2v[n] = w2[l * H_SZ + col];
    }
    const float b2v = b2[l];

    f32x4 acc[8][4];
    #pragma unroll
    for (int m = 0; m < 8; ++m)
        #pragma unroll
        for (int n = 0; n < 4; ++n) {
            acc[m][n][0] = 0.f; acc[m][n][1] = 0.f;
            acc[m][n][2] = 0.f; acc[m][n][3] = 0.f;
        }

    bf16x8 af[4], bfv[4];

    // Prologue: tiles 0,1 staged; VMW(4) retires tile 0 (tile 1 in flight).
    STAGE_A(0, 0); STAGE_B(0, 0);
    STAGE_A(1, 1); STAGE_B(1, 1);
    VMW(4);
    SBAR;

    // 30 tiles in the rotating main loop; tiles 30,31 in the tail.
    #pragma unroll 1
    for (int i = 0; i < 10; ++i) {
        const int t = 3 * i;
        TILE(t,     0, 2);
        TILE(t + 1, 1, 0);
        TILE(t + 2, 2, 1);
    }
    // tile 30 (buf 0): nothing to stage; VMW(0) retires tile 31's loads.
    DS_A(0, 0); DS_B(0); SBAR; MFMA_H(0); SBAR;
    DS_A(0, 1);          SBAR; MFMA_H(1); VMW(0); SBAR;
    // tile 31 (buf 1)
    DS_A(1, 0); DS_B(1); SBAR; MFMA_H(0); SBAR;
    DS_A(1, 1);          SBAR; MFMA_H(1);

    // ---- fused epilogue: out[row, l] = sum_h relu(C + b1)*w2 + b2 ----
    #pragma unroll
    for (int mf = 0; mf < 8; ++mf) {
        #pragma unroll
        for (int r = 0; r < 4; ++r) {
            float p = 0.f;
            #pragma unroll
            for (int nf = 0; nf < 4; ++nf) {
                float v = acc[mf][nf][r] + b1v[nf];
                v = fmaxf(v, 0.f);
                p += v * w2v[nf];
            }
            p += __shfl_xor(p, 1);
            p += __shfl_xor(p, 2);
            p += __shfl_xor(p, 4);
            p += __shfl_xor(p, 8);
            if (rl == 0)
                partRed[wr * 128 + mf * 16 + g * 4 + r][wc] = p;
        }
    }
    __syncthreads();
    if (tid < BM) {
        float s = b2v;
        #pragma unroll
        for (int w = 0; w < 4; ++w) s += partRed[tid][w];
        out[(size_t)(m0 + tid) * L_SZ + l] = s;
    }
}

extern "C" void kernel_launch(void* const* d_in, const int* in_sizes, int n_in,
                              void* d_out, int out_size, void* d_ws, size_t ws_size,
                              hipStream_t stream) {
    const float* x  = (const float*)d_in[0];
    const float* W1 = (const float*)d_in[1];
    const float* b1 = (const float*)d_in[2];
    const float* W2 = (const float*)d_in[3];
    const float* b2 = (const float*)d_in[4];
    float* out = (float*)d_out;

    unsigned short* xb  = (unsigned short*)d_ws;                 // 16 MB
    unsigned short* w1t = xb + (size_t)B_SZ * D_SZ;              // 32 MB

    cvt_x_kernel<<<(B_SZ * D_SZ / 4) / 256, 256, 0, stream>>>(x, xb);
    transpose_w1_kernel<<<L_SZ * 16 * 4, 256, 0, stream>>>(W1, w1t);
    ffn_gemm_kernel<<<(B_SZ / BM) * L_SZ, 512, 0, stream>>>(xb, w1t, b1, W2, b2, out);
}